// Round 4
// baseline (258.160 us; speedup 1.0000x reference)
//
#include <hip/hip_runtime.h>

// Problem constants
#define N_ 32
#define T_ 1024
#define E_ 64
#define H_ 8
#define D_ 8
#define KS_ 4            // key splits per (n,h)
#define KCH (T_/KS_)     // 256 keys per block
#define QPT 8            // queries per thread (128-thread blocks)

#if __has_builtin(__builtin_amdgcn_exp2f)
#define EXP2(x) __builtin_amdgcn_exp2f(x)
#else
#define EXP2(x) exp2f(x)
#endif

#define LOG2E 1.44269504f
#define CLIP2 (5.0f * LOG2E)      // clip bound in exp2 domain
#define QSCALE (0.125f * LOG2E)   // (1/sqrt(E)) * log2e folded into q

// ---------------------------------------------------------------------------
// attn_fused: block = one (n,h) x one 256-key chunk; 128 threads, 8 q/thread.
//  - K/V chunk staged+projected into LDS (broadcast reads in main loop)
//  - logits bounded in [-5,5] by the reference clip -> exp cannot overflow ->
//    single-pass softmax partials (additive across key-splits)
//  - partial layout po[(nh*KS+ks)*T + t]: lane-contiguous 32B writes
// grid = (KS_, N*H), block = 128.
// ---------------------------------------------------------------------------
__global__ __launch_bounds__(128, 2) void attn_fused(
    const float* __restrict__ vals,
    const float* __restrict__ keys,
    const float* __restrict__ qrys,
    const float* __restrict__ Wv,
    const float* __restrict__ Wk,
    const float* __restrict__ Wq,
    float4* __restrict__ po, float* __restrict__ ps)
{
    __shared__ float Ks[KCH * 8];    // [key][d], 8 KB
    __shared__ float Vs[KCH * 8];    // 8 KB
    __shared__ float Wks[64], Wvs[64], Wqs[64];

    const int tid = threadIdx.x;     // 0..127
    const int ks  = blockIdx.x;      // 0..KS_-1
    const int nh  = blockIdx.y;      // n*H + h
    const int n   = nh >> 3;
    const int h   = nh & 7;

    if (tid < 64) { Wks[tid] = Wk[tid]; Wqs[tid] = Wq[tid]; }
    else          { Wvs[tid - 64] = Wv[tid - 64]; }
    __syncthreads();

    // ---- stage + project this block's 256-key K/V chunk (2 keys/thread) ----
    #pragma unroll
    for (int r = 0; r < 2; ++r) {
        const int key = r * 128 + tid;               // local key 0..255
        const int tk  = ks * KCH + key;              // global key index
        const float* kin = keys + (size_t)(n * T_ + tk) * E_ + h * D_;
        const float* vin = vals + (size_t)(n * T_ + tk) * E_ + h * D_;
        float4 k0 = ((const float4*)kin)[0], k1 = ((const float4*)kin)[1];
        float4 v0 = ((const float4*)vin)[0], v1 = ((const float4*)vin)[1];
        float xk[8] = {k0.x,k0.y,k0.z,k0.w,k1.x,k1.y,k1.z,k1.w};
        float xv[8] = {v0.x,v0.y,v0.z,v0.w,v1.x,v1.y,v1.z,v1.w};
        float rk[8], rv[8];
        #pragma unroll
        for (int d = 0; d < 8; ++d) {
            float ak = 0.f, av = 0.f;
            #pragma unroll
            for (int e = 0; e < 8; ++e) {
                ak += xk[e] * Wks[d*8 + e];
                av += xv[e] * Wvs[d*8 + e];
            }
            rk[d] = ak; rv[d] = av;
        }
        ((float4*)&Ks[key*8])[0] = make_float4(rk[0],rk[1],rk[2],rk[3]);
        ((float4*)&Ks[key*8])[1] = make_float4(rk[4],rk[5],rk[6],rk[7]);
        ((float4*)&Vs[key*8])[0] = make_float4(rv[0],rv[1],rv[2],rv[3]);
        ((float4*)&Vs[key*8])[1] = make_float4(rv[4],rv[5],rv[6],rv[7]);
    }

    // ---- load + project this thread's 8 queries ----
    float q[QPT][8], o[QPT][8], sum[QPT];
    #pragma unroll
    for (int j = 0; j < QPT; ++j) {
        const int tq = j * 128 + tid;
        const float* qin = qrys + (size_t)(n * T_ + tq) * E_ + h * D_;
        float4 x0 = ((const float4*)qin)[0], x1 = ((const float4*)qin)[1];
        float x[8] = {x0.x,x0.y,x0.z,x0.w,x1.x,x1.y,x1.z,x1.w};
        #pragma unroll
        for (int d = 0; d < 8; ++d) {
            float a = 0.f;
            #pragma unroll
            for (int e = 0; e < 8; ++e) a += x[e] * Wqs[d*8 + e];
            q[j][d] = a * QSCALE;     // fold scale * log2e
            o[j][d] = 0.f;
        }
        sum[j] = 0.f;
    }
    __syncthreads();

    // ---- main loop: 256 keys x 8 queries/thread ----
    #pragma unroll 2
    for (int kk = 0; kk < KCH; ++kk) {
        const float4 k0 = ((const float4*)&Ks[kk*8])[0];
        const float4 k1 = ((const float4*)&Ks[kk*8])[1];
        const float4 v0 = ((const float4*)&Vs[kk*8])[0];
        const float4 v1 = ((const float4*)&Vs[kk*8])[1];
        float w[QPT];
        #pragma unroll
        for (int j = 0; j < QPT; ++j) {
            float d = (q[j][0]*k0.x + q[j][1]*k0.y + q[j][2]*k0.z + q[j][3]*k0.w)
                    + (q[j][4]*k1.x + q[j][5]*k1.y + q[j][6]*k1.z + q[j][7]*k1.w);
            d = fminf(fmaxf(d, -CLIP2), CLIP2);
            w[j] = EXP2(d);
            sum[j] += w[j];
        }
        #pragma unroll
        for (int j = 0; j < QPT; ++j) {
            o[j][0] += w[j]*v0.x; o[j][1] += w[j]*v0.y;
            o[j][2] += w[j]*v0.z; o[j][3] += w[j]*v0.w;
            o[j][4] += w[j]*v1.x; o[j][5] += w[j]*v1.y;
            o[j][6] += w[j]*v1.z; o[j][7] += w[j]*v1.w;
        }
    }

    // ---- write partials: record = (nh*KS + ks)*T + tq (lane-contiguous) ----
    #pragma unroll
    for (int j = 0; j < QPT; ++j) {
        const int tq = j * 128 + tid;
        const int i  = (nh * KS_ + ks) * T_ + tq;
        po[2*i]     = make_float4(o[j][0], o[j][1], o[j][2], o[j][3]);
        po[2*i + 1] = make_float4(o[j][4], o[j][5], o[j][6], o[j][7]);
        ps[i] = sum[j];
    }
}

// ---------------------------------------------------------------------------
// combine: sum KS_ partials per (nh,t), normalize, write attn in [N,H,T,D].
// thread j = nh*T + t; all reads/writes lane-contiguous.
// ---------------------------------------------------------------------------
__global__ __launch_bounds__(256) void combine_kernel(
    const float4* __restrict__ po, const float* __restrict__ ps,
    float* __restrict__ attn)
{
    const int j  = blockIdx.x * 256 + threadIdx.x;   // nh*T + t
    const int nh = j >> 10;
    const int t  = j & 1023;
    float4 a = make_float4(0.f,0.f,0.f,0.f);
    float4 b = make_float4(0.f,0.f,0.f,0.f);
    float s = 0.f;
    #pragma unroll
    for (int ks = 0; ks < KS_; ++ks) {
        const int i = (nh * KS_ + ks) * T_ + t;
        const float4 pa = po[2*i];
        const float4 pb = po[2*i + 1];
        a.x += pa.x; a.y += pa.y; a.z += pa.z; a.w += pa.w;
        b.x += pb.x; b.y += pb.y; b.z += pb.z; b.w += pb.w;
        s += ps[i];
    }
    const float inv = 1.f / s;
    a.x *= inv; a.y *= inv; a.z *= inv; a.w *= inv;
    b.x *= inv; b.y *= inv; b.z *= inv; b.w *= inv;
    ((float4*)attn)[j*2]     = a;
    ((float4*)attn)[j*2 + 1] = b;
}

// ---------------------------------------------------------------------------
// oproj: out[n,t,:] = attn_row @ Wo^T + bo. attn is [N,H,T,D]; the 64-elem
// row for (n,t) is gathered from 8 head-segments (wave-uniform reads -> L2
// broadcast). lane = out-feature, Wo row held in 16 float4 VGPRs, 8 rows/wave.
// ---------------------------------------------------------------------------
__global__ __launch_bounds__(256) void oproj_kernel(
    const float* __restrict__ attn,
    const float* __restrict__ Wo,
    const float* __restrict__ bo,
    float* __restrict__ out)
{
    const int eo   = threadIdx.x & 63;
    const int wave = (blockIdx.x * 256 + threadIdx.x) >> 6;   // 0..4095
    float4 w[16];
    const float4* wrow = (const float4*)(Wo + eo * 64);
    #pragma unroll
    for (int i = 0; i < 16; ++i) w[i] = wrow[i];
    const float bias = bo[eo];

    #pragma unroll 2
    for (int r = 0; r < 8; ++r) {
        const int row = wave * 8 + r;        // n*T + t
        const int n   = row >> 10;
        const int t   = row & 1023;
        const float* xb = attn + ((size_t)(n * H_) * T_ + t) * D_;
        float acc = bias;
        #pragma unroll
        for (int h2 = 0; h2 < 8; ++h2) {
            const float4 xa = ((const float4*)(xb + (size_t)h2 * T_ * D_))[0];
            const float4 xc = ((const float4*)(xb + (size_t)h2 * T_ * D_))[1];
            acc += xa.x*w[2*h2].x + xa.y*w[2*h2].y + xa.z*w[2*h2].z + xa.w*w[2*h2].w
                 + xc.x*w[2*h2+1].x + xc.y*w[2*h2+1].y + xc.z*w[2*h2+1].z + xc.w*w[2*h2+1].w;
        }
        out[(size_t)row * 64 + eo] = acc;
    }
}

// ---------------------------------------------------------------------------
extern "C" void kernel_launch(void* const* d_in, const int* in_sizes, int n_in,
                              void* d_out, int out_size, void* d_ws, size_t ws_size,
                              hipStream_t stream)
{
    const float* vals = (const float*)d_in[0];
    const float* keys = (const float*)d_in[1];
    const float* qrys = (const float*)d_in[2];
    const float* Wv   = (const float*)d_in[3];
    const float* Wk   = (const float*)d_in[4];
    const float* Wq   = (const float*)d_in[5];
    const float* Wo   = (const float*)d_in[6];
    const float* bo   = (const float*)d_in[7];

    float* ws = (float*)d_ws;
    // po: N*H*KS*T records x 8 floats = 8,388,608 floats (33.5 MB)
    // ps: N*H*KS*T floats            = 1,048,576 floats ( 4.2 MB)
    // attn [N,H,T,D]:                  2,097,152 floats ( 8.4 MB)
    float4* po   = (float4*)ws;
    float*  ps   = ws + 8388608;
    float*  attn = ws + 8388608 + 1048576;

    attn_fused<<<dim3(KS_, N_ * H_), 128, 0, stream>>>(
        vals, keys, qrys, Wv, Wk, Wq, po, ps);
    combine_kernel<<<(N_ * H_ * T_) / 256, 256, 0, stream>>>(po, ps, attn);
    oproj_kernel<<<1024, 256, 0, stream>>>(attn, Wo, bo, (float*)d_out);
}

// Round 5
// 228.796 us; speedup vs baseline: 1.1283x; 1.1283x over previous
//
#include <hip/hip_runtime.h>

// Problem constants
#define N_ 32
#define T_ 1024
#define E_ 64
#define H_ 8
#define D_ 8

#define LOG2E 1.44269504f
#define CLIP2 (5.0f * LOG2E)      // clip bound in exp2 domain
#define QSCALE (0.125f * LOG2E)   // (1/sqrt(E)) * log2e folded into q

#if __has_builtin(__builtin_amdgcn_exp2f)
#define EXP2(x) __builtin_amdgcn_exp2f(x)
#else
#define EXP2(x) exp2f(x)
#endif

typedef __attribute__((ext_vector_type(8))) short  frag8;   // 8 bf16 (4 VGPR)
typedef __attribute__((ext_vector_type(4))) float  fragf4;  // 4 fp32 acc

#define VTP 1048   // Vt row pitch in ushort: 12d mod 32 banks -> conflict-free
#define PP  40     // P row pitch in ushort (80B): 20q mod 32 -> 2-way (free)

__device__ __forceinline__ unsigned short f2bf(float x) {
    union { float f; unsigned int u; } c; c.f = x;
    return (unsigned short)((c.u + 0x7FFFu + ((c.u >> 16) & 1u)) >> 16);
}
__device__ __forceinline__ unsigned int pk2(float a, float b) {
    return (unsigned int)f2bf(a) | ((unsigned int)f2bf(b) << 16);
}
__device__ __forceinline__ float ec(float s) {   // clip in exp2 domain + exp2
    return EXP2(fminf(fmaxf(s, -CLIP2), CLIP2));
}

// ---------------------------------------------------------------------------
// attn_mfma: block = (n,h) x 256-query quarter; 256 thr = 4 waves.
// Stage: K,Q projected->bf16 row-major LDS; V projected->bf16 TRANSPOSED
// (Vt[d][key], row d=8 = ones for the softmax row-sum via MFMA).
// Main loop (no barriers): per 32-key chunk per q-tile:
//   S^T tiles = mfma(Kfrag, Qfrag)   -> lane holds q=lane&15, keys=quad*4+r
//   P row-major via 2x ds_write_b64  -> re-read as PV A-frag (1x b128)
//   O += mfma(Pfrag, Vtfrag)         -> col d (d=8 is the exp-sum)
// Epilogue: shfl the d=8 column for row sums, normalize, store [N,H,T,D].
// ---------------------------------------------------------------------------
__global__ __launch_bounds__(256, 3) void attn_mfma(
    const float* __restrict__ vals,
    const float* __restrict__ keys,
    const float* __restrict__ qrys,
    const float* __restrict__ Wv,
    const float* __restrict__ Wk,
    const float* __restrict__ Wq,
    float* __restrict__ attnb)
{
    __shared__ __align__(16) unsigned short Ks[T_ * 8];      // 16 KB [key][d]
    __shared__ __align__(16) unsigned short Qs[256 * 8];     //  4 KB [q][d]
    __shared__ __align__(16) unsigned short Vt[9 * VTP];     // 18.9 KB [d][key]
    __shared__ __align__(16) unsigned short Pw[4][16 * PP];  //  5 KB per-wave P
    __shared__ float Wqs[64], Wks[64], Wvs[64];

    const int tid = threadIdx.x;
    const int qq  = blockIdx.x;          // query quarter 0..3
    const int nh  = blockIdx.y;          // n*H + h
    const int n   = nh >> 3, h = nh & 7;

    if (tid < 64) { Wqs[tid] = Wq[tid]; Wks[tid] = Wk[tid]; Wvs[tid] = Wv[tid]; }
    __syncthreads();

    // ---- stage all 1024 keys: K rows (bf16) + V transposed (bf16 + ones) ----
    #pragma unroll
    for (int r = 0; r < 4; ++r) {
        const int k = r * 256 + tid;
        const float* kin = keys + (size_t)(n * T_ + k) * E_ + h * D_;
        const float* vin = vals + (size_t)(n * T_ + k) * E_ + h * D_;
        const float4 a0 = ((const float4*)kin)[0], a1 = ((const float4*)kin)[1];
        const float4 b0 = ((const float4*)vin)[0], b1 = ((const float4*)vin)[1];
        const float xk[8] = {a0.x,a0.y,a0.z,a0.w,a1.x,a1.y,a1.z,a1.w};
        const float xv[8] = {b0.x,b0.y,b0.z,b0.w,b1.x,b1.y,b1.z,b1.w};
        unsigned short rk[8];
        #pragma unroll
        for (int d = 0; d < 8; ++d) {
            float ak = 0.f, av = 0.f;
            #pragma unroll
            for (int e = 0; e < 8; ++e) {
                ak += xk[e] * Wks[d*8 + e];
                av += xv[e] * Wvs[d*8 + e];
            }
            rk[d] = f2bf(ak);
            Vt[d * VTP + k] = f2bf(av);
        }
        uint4 pkk;
        pkk.x = (unsigned int)rk[0] | ((unsigned int)rk[1] << 16);
        pkk.y = (unsigned int)rk[2] | ((unsigned int)rk[3] << 16);
        pkk.z = (unsigned int)rk[4] | ((unsigned int)rk[5] << 16);
        pkk.w = (unsigned int)rk[6] | ((unsigned int)rk[7] << 16);
        ((uint4*)&Ks[k * 8])[0] = pkk;
        Vt[8 * VTP + k] = 0x3F80;        // 1.0 in bf16 (ones row -> row sums)
    }
    // ---- stage this block's 256 queries (projected, pre-scaled, bf16) ----
    {
        const int qg = qq * 256 + tid;
        const float* qin = qrys + (size_t)(n * T_ + qg) * E_ + h * D_;
        const float4 a0 = ((const float4*)qin)[0], a1 = ((const float4*)qin)[1];
        const float xq[8] = {a0.x,a0.y,a0.z,a0.w,a1.x,a1.y,a1.z,a1.w};
        unsigned short rq[8];
        #pragma unroll
        for (int d = 0; d < 8; ++d) {
            float aq = 0.f;
            #pragma unroll
            for (int e = 0; e < 8; ++e) aq += xq[e] * Wqs[d*8 + e];
            rq[d] = f2bf(aq * QSCALE);
        }
        uint4 pkq;
        pkq.x = (unsigned int)rq[0] | ((unsigned int)rq[1] << 16);
        pkq.y = (unsigned int)rq[2] | ((unsigned int)rq[3] << 16);
        pkq.z = (unsigned int)rq[4] | ((unsigned int)rq[5] << 16);
        pkq.w = (unsigned int)rq[6] | ((unsigned int)rq[7] << 16);
        ((uint4*)&Qs[tid * 8])[0] = pkq;
    }
    __syncthreads();

    const int wave = tid >> 6, lane = tid & 63;
    const int quad = lane >> 4, l15 = lane & 15;
    unsigned short* myP = Pw[wave];

    // Q B-frags for this wave's 4 q-tiles (B[k=quad*8+j][n=lane&15]; quads 1-3
    // correspond to k=8..31 where the K A-frag is zero, so their content is moot)
    frag8 qf[4];
    #pragma unroll
    for (int qt = 0; qt < 4; ++qt)
        qf[qt] = *(const frag8*)&Qs[(wave * 64 + qt * 16 + l15) * 8];

    fragf4 O[4];
    #pragma unroll
    for (int qt = 0; qt < 4; ++qt) O[qt] = (fragf4){0.f, 0.f, 0.f, 0.f};

    const frag8 zf = (frag8){0,0,0,0,0,0,0,0};
    const fragf4 zc = (fragf4){0.f, 0.f, 0.f, 0.f};

    for (int ch = 0; ch < 32; ++ch) {
        const int kb = ch * 32;
        frag8 kf0 = zf, kf1 = zf, vf = zf;
        if (lane < 16) {                         // A[m=key][k=d]: quad0 real, rest 0
            kf0 = *(const frag8*)&Ks[(kb + l15) * 8];
            kf1 = *(const frag8*)&Ks[(kb + 16 + l15) * 8];
        }
        if (l15 <= 8)                            // B[k=key][n=d]: d 0..7 + ones col 8
            vf = *(const frag8*)&Vt[l15 * VTP + kb + quad * 8];

        #pragma unroll
        for (int qt = 0; qt < 4; ++qt) {
            fragf4 s0 = __builtin_amdgcn_mfma_f32_16x16x32_bf16(kf0, qf[qt], zc, 0, 0, 0);
            fragf4 s1 = __builtin_amdgcn_mfma_f32_16x16x32_bf16(kf1, qf[qt], zc, 0, 0, 0);
            // exp2(clip(S)) -> bf16, pack; lane's 4 keys are consecutive -> b64
            uint2 w0 = make_uint2(pk2(ec(s0[0]), ec(s0[1])), pk2(ec(s0[2]), ec(s0[3])));
            uint2 w1 = make_uint2(pk2(ec(s1[0]), ec(s1[1])), pk2(ec(s1[2]), ec(s1[3])));
            *(uint2*)&myP[l15 * PP + quad * 4]      = w0;   // keys kb + quad*4 + r
            *(uint2*)&myP[l15 * PP + 16 + quad * 4] = w1;   // keys kb+16 + quad*4 + r
            // read back as PV A-frag: A[m=q][k=quad*8+j] (in-wave DS order is safe)
            frag8 pf = *(const frag8*)&myP[l15 * PP + quad * 8];
            O[qt] = __builtin_amdgcn_mfma_f32_16x16x32_bf16(pf, vf, O[qt], 0, 0, 0);
        }
    }

    // ---- epilogue: row sums live in column d==8 (lanes (quad<<4)|8) ----
    const int src = (lane & 48) | 8;
    #pragma unroll
    for (int qt = 0; qt < 4; ++qt) {
        fragf4 o = O[qt];
        const float s0 = __shfl(o[0], src, 64);
        const float s1 = __shfl(o[1], src, 64);
        const float s2 = __shfl(o[2], src, 64);
        const float s3 = __shfl(o[3], src, 64);
        if (l15 < 8) {
            const int qg = qq * 256 + wave * 64 + qt * 16 + quad * 4;
            float* ob = attnb + ((size_t)nh * T_ + qg) * 8 + l15;
            ob[0]  = o[0] / s0;
            ob[8]  = o[1] / s1;
            ob[16] = o[2] / s2;
            ob[24] = o[3] / s3;
        }
    }
}

// ---------------------------------------------------------------------------
// oproj: out[n,t,:] = attn_row @ Wo^T + bo. attn is [N,H,T,D]; the 64-elem
// row for (n,t) is gathered from 8 head-segments (wave-uniform reads -> L2
// broadcast). lane = out-feature, Wo row held in 16 float4 VGPRs, 8 rows/wave.
// ---------------------------------------------------------------------------
__global__ __launch_bounds__(256) void oproj_kernel(
    const float* __restrict__ attn,
    const float* __restrict__ Wo,
    const float* __restrict__ bo,
    float* __restrict__ out)
{
    const int eo   = threadIdx.x & 63;
    const int wave = (blockIdx.x * 256 + threadIdx.x) >> 6;   // 0..4095
    float4 w[16];
    const float4* wrow = (const float4*)(Wo + eo * 64);
    #pragma unroll
    for (int i = 0; i < 16; ++i) w[i] = wrow[i];
    const float bias = bo[eo];

    #pragma unroll 2
    for (int r = 0; r < 8; ++r) {
        const int row = wave * 8 + r;        // n*T + t
        const int n   = row >> 10;
        const int t   = row & 1023;
        const float* xb = attn + ((size_t)(n * H_) * T_ + t) * D_;
        float acc = bias;
        #pragma unroll
        for (int h2 = 0; h2 < 8; ++h2) {
            const float4 xa = ((const float4*)(xb + (size_t)h2 * T_ * D_))[0];
            const float4 xc = ((const float4*)(xb + (size_t)h2 * T_ * D_))[1];
            acc += xa.x*w[2*h2].x + xa.y*w[2*h2].y + xa.z*w[2*h2].z + xa.w*w[2*h2].w
                 + xc.x*w[2*h2+1].x + xc.y*w[2*h2+1].y + xc.z*w[2*h2+1].z + xc.w*w[2*h2+1].w;
        }
        out[(size_t)row * 64 + eo] = acc;
    }
}

// ---------------------------------------------------------------------------
extern "C" void kernel_launch(void* const* d_in, const int* in_sizes, int n_in,
                              void* d_out, int out_size, void* d_ws, size_t ws_size,
                              hipStream_t stream)
{
    const float* vals = (const float*)d_in[0];
    const float* keys = (const float*)d_in[1];
    const float* qrys = (const float*)d_in[2];
    const float* Wv   = (const float*)d_in[3];
    const float* Wk   = (const float*)d_in[4];
    const float* Wq   = (const float*)d_in[5];
    const float* Wo   = (const float*)d_in[6];
    const float* bo   = (const float*)d_in[7];

    float* attnb = (float*)d_ws;   // [N,H,T,D] fp32, 8.4 MB

    attn_mfma<<<dim3(4, N_ * H_), 256, 0, stream>>>(
        vals, keys, qrys, Wv, Wk, Wq, attnb);
    oproj_kernel<<<1024, 256, 0, stream>>>(attnb, Wo, bo, (float*)d_out);
}

// Round 7
// 199.997 us; speedup vs baseline: 1.2908x; 1.1440x over previous
//
#include <hip/hip_runtime.h>

// Problem constants
#define N_ 32
#define T_ 1024
#define E_ 64
#define H_ 8
#define D_ 8

#define LOG2E 1.44269504f
#define CLIP2 (5.0f * LOG2E)      // clip bound in exp2 domain
#define QSCALE (0.125f * LOG2E)   // (1/sqrt(E)) * log2e folded into q

#if __has_builtin(__builtin_amdgcn_exp2f)
#define EXP2(x) __builtin_amdgcn_exp2f(x)
#else
#define EXP2(x) exp2f(x)
#endif

typedef _Float16 half4v __attribute__((ext_vector_type(4)));
typedef float    float4v __attribute__((ext_vector_type(4)));

#define VTP 1052   // Vt row pitch in ushorts: 2104 B (8B-aligned), word-stride
                   // 526 = 14 mod 32 -> <=2-way for rows 0..8 (free)

// pack two floats -> f16x2 (RTZ), as raw u32 (cvt_pkrtz returns __fp16x2;
// bit-cast through a union to avoid the _Float16/__fp16 type mismatch)
__device__ __forceinline__ unsigned int pkh(float a, float b) {
    auto h = __builtin_amdgcn_cvt_pkrtz(a, b);
    union { decltype(h) h2; unsigned int u; } c; c.h2 = h; return c.u;
}
__device__ __forceinline__ unsigned short f2h(float x) {
    union { _Float16 f; unsigned short u; } c; c.f = (_Float16)x; return c.u;
}
__device__ __forceinline__ float ec(float s) {   // clip (exp2 domain) + exp2
    return EXP2(fminf(fmaxf(s, -CLIP2), CLIP2));
}

// ---------------------------------------------------------------------------
// attn_mfma: block = (n,h) x 512-query half; 256 thr = 4 waves, 8 q-tiles/wave.
// All 1024 keys staged once per block: K[key][d] f16 (pitch 8), V TRANSPOSED
// Vt[d][key] f16 (row d=8 = ones -> row-sums via MFMA), Q[q][d] f16.
// Main loop per 16-key tile (NO barriers, NO P round-trip):
//   S^T = mfma_16x16x16(Kfrag, Qfrag)    lane: q=lane&15, keys=quad*4+reg
//   P   = cvt_pkrtz(exp2(clip(S)))       -> IS the PV A-frag (layouts match!)
//   O  += mfma_16x16x16(P, Vtfrag)       cols: d=lane&15 (col 8 = exp-sum)
// Q-frag quads 2,3 zeroed (k=8..15); K-frag quads 2,3 alias real finite data
// via qsel=(quad&1)*4, so zeroed-Q x finite-K contributes exactly 0.
// ---------------------------------------------------------------------------
__global__ __launch_bounds__(256, 2) void attn_mfma(
    const float* __restrict__ vals,
    const float* __restrict__ keys,
    const float* __restrict__ qrys,
    const float* __restrict__ Wv,
    const float* __restrict__ Wk,
    const float* __restrict__ Wq,
    float* __restrict__ attnb)
{
    __shared__ __align__(16) unsigned short Ks[T_ * 8 + 8];   // 16.4 KB [key][d]
    __shared__ __align__(16) unsigned short Qs[512 * 8];      //  8   KB [q][d]
    __shared__ __align__(16) unsigned short Vt[9 * VTP + 8];  // 18.9 KB [d][key]
    __shared__ float Wqs[64], Wks[64], Wvs[64];

    const int tid = threadIdx.x;
    const int qh  = blockIdx.x;          // query half 0..1
    const int nh  = blockIdx.y;          // n*H + h
    const int n   = nh >> 3, h = nh & 7;

    if (tid < 64) { Wqs[tid] = Wq[tid]; Wks[tid] = Wk[tid]; Wvs[tid] = Wv[tid]; }
    __syncthreads();

    // ---- stage all 1024 keys: K rows f16 + V transposed f16 (+ ones row) ----
    #pragma unroll
    for (int r = 0; r < 4; ++r) {
        const int k = r * 256 + tid;
        const float* kin = keys + (size_t)(n * T_ + k) * E_ + h * D_;
        const float* vin = vals + (size_t)(n * T_ + k) * E_ + h * D_;
        const float4 a0 = ((const float4*)kin)[0], a1 = ((const float4*)kin)[1];
        const float4 b0 = ((const float4*)vin)[0], b1 = ((const float4*)vin)[1];
        const float xk[8] = {a0.x,a0.y,a0.z,a0.w,a1.x,a1.y,a1.z,a1.w};
        const float xv[8] = {b0.x,b0.y,b0.z,b0.w,b1.x,b1.y,b1.z,b1.w};
        float rk[8];
        #pragma unroll
        for (int d = 0; d < 8; ++d) {
            float ak = 0.f, av = 0.f;
            #pragma unroll
            for (int e = 0; e < 8; ++e) {
                ak += xk[e] * Wks[d*8 + e];
                av += xv[e] * Wvs[d*8 + e];
            }
            rk[d] = ak;
            Vt[d * VTP + k] = f2h(av);
        }
        uint4 kw;
        kw.x = pkh(rk[0], rk[1]);
        kw.y = pkh(rk[2], rk[3]);
        kw.z = pkh(rk[4], rk[5]);
        kw.w = pkh(rk[6], rk[7]);
        ((uint4*)&Ks[k * 8])[0] = kw;
        Vt[8 * VTP + k] = 0x3C00;        // f16 1.0: ones row -> softmax sums
    }
    // ---- stage this block's 512 queries (projected, pre-scaled, f16) ----
    #pragma unroll
    for (int r = 0; r < 2; ++r) {
        const int qidx = r * 256 + tid;                 // local 0..511
        const int qg   = qh * 512 + qidx;               // global query
        const float* qin = qrys + (size_t)(n * T_ + qg) * E_ + h * D_;
        const float4 a0 = ((const float4*)qin)[0], a1 = ((const float4*)qin)[1];
        const float xq[8] = {a0.x,a0.y,a0.z,a0.w,a1.x,a1.y,a1.z,a1.w};
        float rq[8];
        #pragma unroll
        for (int d = 0; d < 8; ++d) {
            float aq = 0.f;
            #pragma unroll
            for (int e = 0; e < 8; ++e) aq += xq[e] * Wqs[d*8 + e];
            rq[d] = aq * QSCALE;
        }
        uint4 qw;
        qw.x = pkh(rq[0], rq[1]);
        qw.y = pkh(rq[2], rq[3]);
        qw.z = pkh(rq[4], rq[5]);
        qw.w = pkh(rq[6], rq[7]);
        ((uint4*)&Qs[qidx * 8])[0] = qw;
    }
    __syncthreads();

    const int wave = tid >> 6, lane = tid & 63;
    const int quad = lane >> 4, l15 = lane & 15;
    const int qsel = (quad & 1) * 4;     // quads 2,3 mirror 0,1 (finite alias)

    // ---- hoist the 8 Q B-frags; zero quads 2,3 (k=d=8..15 must be zero) ----
    half4v qf[8];
    #pragma unroll
    for (int qt = 0; qt < 8; ++qt) {
        half4v v = *(const half4v*)&Qs[(wave * 128 + qt * 16 + l15) * 8 + qsel];
        qf[qt] = (lane < 32) ? v : (half4v)(_Float16)0;
    }
    float4v O[8];
    #pragma unroll
    for (int qt = 0; qt < 8; ++qt) O[qt] = (float4v){0.f,0.f,0.f,0.f};
    const float4v zc = (float4v){0.f,0.f,0.f,0.f};

    const unsigned short* vrow = &Vt[(l15 < 8 ? l15 : 8) * VTP];

    // ---- main loop: 64 tiles of 16 keys ----
    for (int kb = 0; kb < T_; kb += 16) {
        const half4v kf = *(const half4v*)&Ks[(kb + l15) * 8 + qsel];
        const half4v vf = *(const half4v*)&vrow[kb + quad * 4];
        #pragma unroll
        for (int qt = 0; qt < 8; ++qt) {
            float4v s = __builtin_amdgcn_mfma_f32_16x16x16f16(kf, qf[qt], zc, 0, 0, 0);
            union { unsigned int u[2]; half4v h; } pc;
            pc.u[0] = pkh(ec(s[0]), ec(s[1]));
            pc.u[1] = pkh(ec(s[2]), ec(s[3]));
            O[qt] = __builtin_amdgcn_mfma_f32_16x16x16f16(pc.h, vf, O[qt], 0, 0, 0);
        }
    }

    // ---- epilogue: row sums live in col d==8 (lanes (quad<<4)|8) ----
    const int src = (lane & 48) | 8;
    #pragma unroll
    for (int qt = 0; qt < 8; ++qt) {
        float4v o = O[qt];
        const float s0 = __shfl(o[0], src, 64);
        const float s1 = __shfl(o[1], src, 64);
        const float s2 = __shfl(o[2], src, 64);
        const float s3 = __shfl(o[3], src, 64);
        if (l15 < 8) {
            const int qg = qh * 512 + wave * 128 + qt * 16 + quad * 4;
            float* ob = attnb + ((size_t)nh * T_ + qg) * 8 + l15;
            ob[0]  = o[0] / s0;
            ob[8]  = o[1] / s1;
            ob[16] = o[2] / s2;
            ob[24] = o[3] / s3;
        }
    }
}

// ---------------------------------------------------------------------------
// oproj: out[n,t,:] = attn_row @ Wo^T + bo. attn is [N,H,T,D]; the 64-elem
// row for (n,t) is gathered from 8 head-segments (wave-uniform reads -> L2
// broadcast). lane = out-feature, Wo row held in 16 float4 VGPRs, 8 rows/wave.
// ---------------------------------------------------------------------------
__global__ __launch_bounds__(256) void oproj_kernel(
    const float* __restrict__ attn,
    const float* __restrict__ Wo,
    const float* __restrict__ bo,
    float* __restrict__ out)
{
    const int eo   = threadIdx.x & 63;
    const int wave = (blockIdx.x * 256 + threadIdx.x) >> 6;   // 0..4095
    float4 w[16];
    const float4* wrow = (const float4*)(Wo + eo * 64);
    #pragma unroll
    for (int i = 0; i < 16; ++i) w[i] = wrow[i];
    const float bias = bo[eo];

    #pragma unroll 2
    for (int r = 0; r < 8; ++r) {
        const int row = wave * 8 + r;        // n*T + t
        const int n   = row >> 10;
        const int t   = row & 1023;
        const float* xb = attn + ((size_t)(n * H_) * T_ + t) * D_;
        float acc = bias;
        #pragma unroll
        for (int h2 = 0; h2 < 8; ++h2) {
            const float4 xa = ((const float4*)(xb + (size_t)h2 * T_ * D_))[0];
            const float4 xc = ((const float4*)(xb + (size_t)h2 * T_ * D_))[1];
            acc += xa.x*w[2*h2].x + xa.y*w[2*h2].y + xa.z*w[2*h2].z + xa.w*w[2*h2].w
                 + xc.x*w[2*h2+1].x + xc.y*w[2*h2+1].y + xc.z*w[2*h2+1].z + xc.w*w[2*h2+1].w;
        }
        out[(size_t)row * 64 + eo] = acc;
    }
}

// ---------------------------------------------------------------------------
extern "C" void kernel_launch(void* const* d_in, const int* in_sizes, int n_in,
                              void* d_out, int out_size, void* d_ws, size_t ws_size,
                              hipStream_t stream)
{
    const float* vals = (const float*)d_in[0];
    const float* keys = (const float*)d_in[1];
    const float* qrys = (const float*)d_in[2];
    const float* Wv   = (const float*)d_in[3];
    const float* Wk   = (const float*)d_in[4];
    const float* Wq   = (const float*)d_in[5];
    const float* Wo   = (const float*)d_in[6];
    const float* bo   = (const float*)d_in[7];

    float* attnb = (float*)d_ws;   // [N,H,T,D] fp32, 8.4 MB

    attn_mfma<<<dim3(2, N_ * H_), 256, 0, stream>>>(
        vals, keys, qrys, Wv, Wk, Wq, attnb);
    oproj_kernel<<<1024, 256, 0, stream>>>(attnb, Wo, bo, (float*)d_out);
}